// Round 16
// baseline (50.224 us; speedup 1.0000x reference)
//
#include <hip/hip_runtime.h>

// Problem: B=8, N=2048, K=32, C=256, COND=512 — ALL FLOAT32 I/O, coords int32.
// Output: f32 [8,2048,256]
// ws layout == r6-proven 10649600 B: gbp 32K @0, Wp 128K @32768,
// ew 2M @163840, nnf 8M @2260992.

typedef unsigned short u16;
typedef unsigned int u32;

typedef __attribute__((ext_vector_type(8))) __bf16 bf16x8;
typedef __attribute__((ext_vector_type(4))) __bf16 bf16x4;
typedef __attribute__((ext_vector_type(4))) float f32x4;
typedef __attribute__((ext_vector_type(2))) float f32x2;
typedef __attribute__((ext_vector_type(4))) u16 u16x4;

__device__ __forceinline__ float b2f(u16 u) {
  union { u32 i; float f; } x; x.i = ((u32)u) << 16; return x.f;
}

// ---------------------------------------------------------------------------
// K0: prep.
//  blocks   0..31 : W_film repack to MFMA-B fragment order (bf16)
//  blocks  32..95 : cond GEMM partials (r14-proven: 256k × 16col tiles,
//                   16 independent loads in flight per thread)
//  blocks 96..127 : ew = weights * params  (524288 f32, r6-proven)
// ---------------------------------------------------------------------------
__global__ __launch_bounds__(256) void k_prep(const float* __restrict__ Wf,
                                              u16* __restrict__ Wp,
                                              const float* __restrict__ cond,
                                              const float* __restrict__ Wc,
                                              float* __restrict__ gbp,
                                              const float* __restrict__ wts,
                                              const float* __restrict__ prm,
                                              float* __restrict__ ew) {
  int blk = blockIdx.x;
  int tid = threadIdx.x;
  if (blk < 32) {
    int i0 = blk * 2048 + tid;
    #pragma unroll
    for (int u = 0; u < 8; ++u) {
      int i = i0 + u * 256;
      int j  = i & 7;
      int l  = (i >> 3) & 63;
      int ks = (i >> 9) & 7;
      int ct = i >> 12;
      int k   = ks * 32 + ((l >> 4) << 3) + j;
      int col = ct * 16 + (l & 15);
      __bf16 b = (__bf16)Wf[k * 256 + col];
      Wp[i] = *(u16*)&b;
    }
  } else if (blk < 96) {
    int idx = blk - 32;          // 0..63
    int kh = idx >> 5;           // k-half 0..1 (256 k's)
    int ch = idx & 31;           // col-chunk 0..31 (16 cols)

    __shared__ float cf[2048];   // [b][kl]  8 x 256
    __shared__ float red[2048];  // [ks][b*16+col]  16 x 128

    #pragma unroll
    for (int u = 0; u < 8; ++u) {
      int i = u * 256 + tid;
      cf[i] = cond[(i >> 8) * 512 + kh * 256 + (i & 255)];
    }
    __syncthreads();

    int col = tid & 15;
    int ks  = tid >> 4;          // 0..15, each covers 16 k's
    float acc[8] = {0.f,0.f,0.f,0.f,0.f,0.f,0.f,0.f};
    #pragma unroll
    for (int t = 0; t < 16; ++t) {
      int kl = ks * 16 + t;
      float wv = Wc[(kh * 256 + kl) * 512 + ch * 16 + col];
      #pragma unroll
      for (int b = 0; b < 8; ++b)
        acc[b] += cf[b * 256 + kl] * wv;
    }
    #pragma unroll
    for (int b = 0; b < 8; ++b)
      red[ks * 128 + b * 16 + col] = acc[b];
    __syncthreads();

    if (tid < 128) {             // b = tid>>4, col2 = tid&15
      float s = 0.f;
      #pragma unroll
      for (int p = 0; p < 16; ++p)
        s += red[p * 128 + tid];
      gbp[(kh * 8 + (tid >> 4)) * 512 + ch * 16 + (tid & 15)] = s;
    }
  } else {
    int i0 = (blk - 96) * 16384 + tid * 4;
    #pragma unroll
    for (int u = 0; u < 16; ++u) {
      int e = i0 + u * 1024;
      f32x4 w = *(const f32x4*)(wts + e);
      f32x4 p = *(const f32x4*)(prm + e);
      f32x4 r = w * p;
      *(f32x4*)(ew + e) = r;
    }
  }
}

// ---------------------------------------------------------------------------
// K1: nnf = bf16( relu(LN(node_feats @ W_film + b_film) * gamma + beta) )
// 1024 blocks × 256 thr (4 waves), 16 rows/block, 4 blocks/CU.
// DIRECT-GLOBAL A-fragments (no LDS stage, one barrier fewer): lane l loads
// its 32B fragment A[row0+(l&15)][ks*32+(l>>4)*8 ..+8] — 16 full 128B lines
// per instruction pair, L1-shared across the block's 4 waves.
// Wave w owns col-tiles ct=w*4..w*4+3. D frag: col=ct*16+(l&15),
// row=row0+(l>>4)*4+r.
// ---------------------------------------------------------------------------
__global__ __launch_bounds__(256) void k_film(const float* __restrict__ A,
                                              const u16* __restrict__ Wp,
                                              const float* __restrict__ bfm,
                                              const float* __restrict__ gbp,
                                              const float* __restrict__ bcond,
                                              u16* __restrict__ nnf) {
  const int tid = threadIdx.x;
  const int l = tid & 63;
  const int w = tid >> 6;
  const int row0 = blockIdx.x * 16;   // 1024 blocks
  const int b = row0 >> 11;

  __shared__ float red[4][4][2][4];   // [wave][group][s|q][r]

  f32x4 acc[4];
  #pragma unroll
  for (int c = 0; c < 4; ++c) {
    acc[c].x = 0.f; acc[c].y = 0.f; acc[c].z = 0.f; acc[c].w = 0.f;
  }

  const float* arow = A + (size_t)(row0 + (l & 15)) * 256 + ((l >> 4) << 3);
  const u16* wl = Wp + (size_t)l * 8;

  #pragma unroll
  for (int ks = 0; ks < 8; ++ks) {
    f32x4 a0 = *(const f32x4*)(arow + ks * 32);
    f32x4 a1 = *(const f32x4*)(arow + ks * 32 + 4);
    bf16x8 af;
    af[0] = (__bf16)a0.x; af[1] = (__bf16)a0.y;
    af[2] = (__bf16)a0.z; af[3] = (__bf16)a0.w;
    af[4] = (__bf16)a1.x; af[5] = (__bf16)a1.y;
    af[6] = (__bf16)a1.z; af[7] = (__bf16)a1.w;
    #pragma unroll
    for (int c = 0; c < 4; ++c) {
      int ct = w * 4 + c;
      bf16x8 bfr = *(const bf16x8*)(wl + ((size_t)(ct * 8 + ks)) * 512);
      acc[c] = __builtin_amdgcn_mfma_f32_16x16x32_bf16(af, bfr, acc[c], 0, 0, 0);
    }
  }

  const int g = l >> 4;
  float s[4] = {0.f, 0.f, 0.f, 0.f};
  float q[4] = {0.f, 0.f, 0.f, 0.f};
  #pragma unroll
  for (int c = 0; c < 4; ++c) {
    float bcol = bfm[(w * 4 + c) * 16 + (l & 15)];
    #pragma unroll
    for (int r = 0; r < 4; ++r) {
      float v = acc[c][r] + bcol;
      acc[c][r] = v;
      s[r] += v;
      q[r] += v * v;
    }
  }
  #pragma unroll
  for (int m = 1; m < 16; m <<= 1) {
    #pragma unroll
    for (int r = 0; r < 4; ++r) {
      s[r] += __shfl_xor(s[r], m);
      q[r] += __shfl_xor(q[r], m);
    }
  }
  if ((l & 15) == 0) {
    #pragma unroll
    for (int r = 0; r < 4; ++r) {
      red[w][g][0][r] = s[r];
      red[w][g][1][r] = q[r];
    }
  }
  __syncthreads();

  // hoisted gamma/beta per col: 2 k-partials + bias
  float ga[4], be[4];
  #pragma unroll
  for (int c = 0; c < 4; ++c) {
    int col = (w * 4 + c) * 16 + (l & 15);
    ga[c] = gbp[b * 512 + col] + gbp[(8 + b) * 512 + col] + bcond[col] + 1.0f;
    be[c] = gbp[b * 512 + 256 + col] + gbp[(8 + b) * 512 + 256 + col] + bcond[256 + col];
  }

  float mu[4], rs[4];
  #pragma unroll
  for (int r = 0; r < 4; ++r) {
    float ss = red[0][g][0][r] + red[1][g][0][r] + red[2][g][0][r] + red[3][g][0][r];
    float qq = red[0][g][1][r] + red[1][g][1][r] + red[2][g][1][r] + red[3][g][1][r];
    mu[r] = ss * (1.0f / 256.0f);
    float var = qq * (1.0f / 256.0f) - mu[r] * mu[r];
    rs[r] = rsqrtf(var + 1e-5f);
  }

  const int rowb = row0 + (g << 2);
  #pragma unroll
  for (int c = 0; c < 4; ++c) {
    int col = (w * 4 + c) * 16 + (l & 15);
    #pragma unroll
    for (int r = 0; r < 4; ++r) {
      float h = (acc[c][r] - mu[r]) * rs[r];
      float o = fmaxf(h * ga[c] + be[c], 0.f);
      ((__bf16*)nnf)[(size_t)(rowb + r) * 256 + col] = (__bf16)o;
    }
  }
}

// ---------------------------------------------------------------------------
// K2: out = relu(nnf + sum_k ew[k]*nnf[coords[k]])  — column-quarter sliced,
// QUAD-ROW waves + LDS idx/ew broadcast (frozen core); reads precomputed ew.
// ---------------------------------------------------------------------------
__global__ __launch_bounds__(256) void k_gather(const u16* __restrict__ nnf,
                                                const float* __restrict__ ew,
                                                const int* __restrict__ coords,
                                                float* __restrict__ out) {
  const int q  = blockIdx.x >> 10;    // 0..3
  const int rg = blockIdx.x & 1023;   // 16-row group
  const int tid = threadIdx.x;

  __shared__ int   s_idx[512];        // [16 rows][32 k]
  __shared__ float s_ew[512];

  {
    int base = rg * 512 + tid * 2;
    int2  c2 = *(const int2*)(coords + base);
    f32x2 e2 = __builtin_nontemporal_load((const f32x2*)(ew + base));
    s_idx[tid * 2]     = c2.x;
    s_idx[tid * 2 + 1] = c2.y;
    s_ew[tid * 2]      = e2.x;
    s_ew[tid * 2 + 1]  = e2.y;
  }
  __syncthreads();

  const int w = tid >> 6;
  const int l = tid & 63;
  const int g = l >> 4;
  const int m = l & 15;
  const int rl = w * 4 + g;           // row-local 0..15
  const int row = rg * 16 + rl;       // 0..16383
  const int kbase = rl * 32;
  const u16* colp = nnf + q * 64 + m * 4;

  u16x4 v[32];
  #pragma unroll
  for (int k = 0; k < 32; ++k) {
    int idx = s_idx[kbase + k];       // uniform per 16-lane group
    v[k] = *(const u16x4*)(colp + ((size_t)idx << 8));
  }

  float acc[4] = {0.f, 0.f, 0.f, 0.f};
  #pragma unroll
  for (int k = 0; k < 32; ++k) {
    float wgt = s_ew[kbase + k];
    #pragma unroll
    for (int j = 0; j < 4; ++j)
      acc[j] += wgt * b2f(v[k][j]);
  }

  u16x4 sv = *(const u16x4*)(colp + ((size_t)row << 8));
  f32x4 o;
  o.x = fmaxf(b2f(sv.x) + acc[0], 0.f);
  o.y = fmaxf(b2f(sv.y) + acc[1], 0.f);
  o.z = fmaxf(b2f(sv.z) + acc[2], 0.f);
  o.w = fmaxf(b2f(sv.w) + acc[3], 0.f);
  __builtin_nontemporal_store(o, (f32x4*)(out + (size_t)row * 256 + q * 64 + m * 4));
}

// ---------------------------------------------------------------------------
extern "C" void kernel_launch(void* const* d_in, const int* in_sizes, int n_in,
                              void* d_out, int out_size, void* d_ws, size_t ws_size,
                              hipStream_t stream) {
  const float* node = (const float*)d_in[0];
  const float* cond = (const float*)d_in[1];
  const float* Wc   = (const float*)d_in[2];
  const float* bc   = (const float*)d_in[3];
  const float* Wf   = (const float*)d_in[4];
  const float* bf   = (const float*)d_in[5];
  const float* wts  = (const float*)d_in[6];
  const float* prm  = (const float*)d_in[7];
  const int* coords = (const int*)d_in[8];
  float* out = (float*)d_out;

  char* ws = (char*)d_ws;
  float* gbp = (float*)ws;                             // 32 KB
  u16* Wp    = (u16*)(ws + 32768);                     // 128 KB
  float* ew  = (float*)(ws + 163840);                  // 2 MB
  u16* nnf   = (u16*)(ws + 2260992);                   // 8 MB (total 10649600 B, r6-proven)

  k_prep<<<dim3(128), dim3(256), 0, stream>>>(Wf, Wp, cond, Wc, gbp, wts, prm, ew);
  k_film<<<dim3(1024), dim3(256), 0, stream>>>(node, Wp, bf, gbp, bc, nnf);
  k_gather<<<dim3(4096), dim3(256), 0, stream>>>(nnf, ew, coords, out);
}

// Round 17
// 46.665 us; speedup vs baseline: 1.0763x; 1.0763x over previous
//
#include <hip/hip_runtime.h>

// Problem: B=8, N=2048, K=32, C=256, COND=512 — ALL FLOAT32 I/O, coords int32.
// Output: f32 [8,2048,256]
// ws footprint == proven 8552448 bytes (gbp 32K + Wp 128K + nnf 8M).
// This is the r15 configuration verbatim — best measured (45.95 µs).

typedef unsigned short u16;
typedef unsigned int u32;

typedef __attribute__((ext_vector_type(8))) __bf16 bf16x8;
typedef __attribute__((ext_vector_type(4))) __bf16 bf16x4;
typedef __attribute__((ext_vector_type(4))) float f32x4;
typedef __attribute__((ext_vector_type(2))) float f32x2;
typedef __attribute__((ext_vector_type(4))) u16 u16x4;

__device__ __forceinline__ float b2f(u16 u) {
  union { u32 i; float f; } x; x.i = ((u32)u) << 16; return x.f;
}

// ---------------------------------------------------------------------------
// K0: prep.
//  blocks  0..31 : W_film repack to MFMA-B fragment order (bf16)
//  blocks 32..95 : cond GEMM partials — block (kh,ch) owns 256k × 16col of Wc,
//                  16 independent loads in flight per thread.
// ---------------------------------------------------------------------------
__global__ __launch_bounds__(256) void k_prep(const float* __restrict__ Wf,
                                              u16* __restrict__ Wp,
                                              const float* __restrict__ cond,
                                              const float* __restrict__ Wc,
                                              float* __restrict__ gbp) {
  int blk = blockIdx.x;
  int tid = threadIdx.x;
  if (blk < 32) {
    int i0 = blk * 2048 + tid;
    #pragma unroll
    for (int u = 0; u < 8; ++u) {
      int i = i0 + u * 256;
      int j  = i & 7;
      int l  = (i >> 3) & 63;
      int ks = (i >> 9) & 7;
      int ct = i >> 12;
      int k   = ks * 32 + ((l >> 4) << 3) + j;
      int col = ct * 16 + (l & 15);
      __bf16 b = (__bf16)Wf[k * 256 + col];
      Wp[i] = *(u16*)&b;
    }
  } else {
    int idx = blk - 32;          // 0..63
    int kh = idx >> 5;           // k-half 0..1 (256 k's)
    int ch = idx & 31;           // col-chunk 0..31 (16 cols)

    __shared__ float cf[2048];   // [b][kl]  8 x 256
    __shared__ float red[2048];  // [ks][b*16+col]  16 x 128

    #pragma unroll
    for (int u = 0; u < 8; ++u) {
      int i = u * 256 + tid;
      cf[i] = cond[(i >> 8) * 512 + kh * 256 + (i & 255)];
    }
    __syncthreads();

    int col = tid & 15;
    int ks  = tid >> 4;          // 0..15, each covers 16 k's
    float acc[8] = {0.f,0.f,0.f,0.f,0.f,0.f,0.f,0.f};
    #pragma unroll
    for (int t = 0; t < 16; ++t) {
      int kl = ks * 16 + t;
      float wv = Wc[(kh * 256 + kl) * 512 + ch * 16 + col];
      #pragma unroll
      for (int b = 0; b < 8; ++b)
        acc[b] += cf[b * 256 + kl] * wv;
    }
    #pragma unroll
    for (int b = 0; b < 8; ++b)
      red[ks * 128 + b * 16 + col] = acc[b];
    __syncthreads();

    if (tid < 128) {             // b = tid>>4, col2 = tid&15
      float s = 0.f;
      #pragma unroll
      for (int p = 0; p < 16; ++p)
        s += red[p * 128 + tid];
      gbp[(kh * 8 + (tid >> 4)) * 512 + ch * 16 + (tid & 15)] = s;
    }
  }
}

// ---------------------------------------------------------------------------
// K1: nnf = bf16( relu(LN(node_feats @ W_film + b_film) * gamma + beta) )
// 1024 blocks × 256 thr (4 waves), 16 rows/block, 4 blocks/CU, 16 waves/CU.
// A staged to LDS bf16 [16][264] via native-cast cvt_pk (coalesced f32x4
// loads). Wave w owns col-tiles ct=w*4..w*4+3 (32 KB Wp slice per wave).
// D frag: col = ct*16+(l&15), row = row0 + (l>>4)*4 + r
// ---------------------------------------------------------------------------
__global__ __launch_bounds__(256) void k_film(const float* __restrict__ A,
                                              const u16* __restrict__ Wp,
                                              const float* __restrict__ bfm,
                                              const float* __restrict__ gbp,
                                              const float* __restrict__ bcond,
                                              u16* __restrict__ nnf) {
  const int tid = threadIdx.x;
  const int l = tid & 63;
  const int w = tid >> 6;
  const int row0 = blockIdx.x * 16;   // 1024 blocks
  const int b = row0 >> 11;

  __shared__ u16 As[16 * 264];
  __shared__ float red[4][4][2][4];   // [wave][group][s|q][r]

  // Stage: flat coalesced, f32 -> bf16 (cvt_pk), one 8B store per iter
  #pragma unroll
  for (int u = 0; u < 4; ++u) {
    int f = u * 256 + tid;            // f32x4 index
    int row = f >> 6;
    int col = (f & 63) * 4;
    f32x4 v = *(const f32x4*)(A + (size_t)(row0 + row) * 256 + col);
    bf16x4 pk;
    pk[0] = (__bf16)v.x; pk[1] = (__bf16)v.y;
    pk[2] = (__bf16)v.z; pk[3] = (__bf16)v.w;
    *(bf16x4*)(As + row * 264 + col) = pk;
  }
  __syncthreads();

  f32x4 acc[4];
  #pragma unroll
  for (int c = 0; c < 4; ++c) {
    acc[c].x = 0.f; acc[c].y = 0.f; acc[c].z = 0.f; acc[c].w = 0.f;
  }

  const u16* asrc = As + (l & 15) * 264 + ((l >> 4) << 3);
  const u16* wl = Wp + (size_t)l * 8;

  #pragma unroll
  for (int ks = 0; ks < 8; ++ks) {
    bf16x8 af = *(const bf16x8*)(asrc + ks * 32);
    #pragma unroll
    for (int c = 0; c < 4; ++c) {
      int ct = w * 4 + c;
      bf16x8 bfr = *(const bf16x8*)(wl + ((size_t)(ct * 8 + ks)) * 512);
      acc[c] = __builtin_amdgcn_mfma_f32_16x16x32_bf16(af, bfr, acc[c], 0, 0, 0);
    }
  }

  const int g = l >> 4;
  float s[4] = {0.f, 0.f, 0.f, 0.f};
  float q[4] = {0.f, 0.f, 0.f, 0.f};
  #pragma unroll
  for (int c = 0; c < 4; ++c) {
    float bcol = bfm[(w * 4 + c) * 16 + (l & 15)];
    #pragma unroll
    for (int r = 0; r < 4; ++r) {
      float v = acc[c][r] + bcol;
      acc[c][r] = v;
      s[r] += v;
      q[r] += v * v;
    }
  }
  #pragma unroll
  for (int m = 1; m < 16; m <<= 1) {
    #pragma unroll
    for (int r = 0; r < 4; ++r) {
      s[r] += __shfl_xor(s[r], m);
      q[r] += __shfl_xor(q[r], m);
    }
  }
  if ((l & 15) == 0) {
    #pragma unroll
    for (int r = 0; r < 4; ++r) {
      red[w][g][0][r] = s[r];
      red[w][g][1][r] = q[r];
    }
  }
  __syncthreads();

  // hoisted gamma/beta per col: 2 k-partials + bias
  float ga[4], be[4];
  #pragma unroll
  for (int c = 0; c < 4; ++c) {
    int col = (w * 4 + c) * 16 + (l & 15);
    ga[c] = gbp[b * 512 + col] + gbp[(8 + b) * 512 + col] + bcond[col] + 1.0f;
    be[c] = gbp[b * 512 + 256 + col] + gbp[(8 + b) * 512 + 256 + col] + bcond[256 + col];
  }

  float mu[4], rs[4];
  #pragma unroll
  for (int r = 0; r < 4; ++r) {
    float ss = red[0][g][0][r] + red[1][g][0][r] + red[2][g][0][r] + red[3][g][0][r];
    float qq = red[0][g][1][r] + red[1][g][1][r] + red[2][g][1][r] + red[3][g][1][r];
    mu[r] = ss * (1.0f / 256.0f);
    float var = qq * (1.0f / 256.0f) - mu[r] * mu[r];
    rs[r] = rsqrtf(var + 1e-5f);
  }

  const int rowb = row0 + (g << 2);
  #pragma unroll
  for (int c = 0; c < 4; ++c) {
    int col = (w * 4 + c) * 16 + (l & 15);
    #pragma unroll
    for (int r = 0; r < 4; ++r) {
      float h = (acc[c][r] - mu[r]) * rs[r];
      float o = fmaxf(h * ga[c] + be[c], 0.f);
      ((__bf16*)nnf)[(size_t)(rowb + r) * 256 + col] = (__bf16)o;
    }
  }
}

// ---------------------------------------------------------------------------
// K2: out = relu(nnf + sum_k ew[k]*nnf[coords[k]])  — column-quarter sliced,
// QUAD-ROW waves + LDS idx/ew broadcast (r9 structure — frozen, proven).
// Block = 4 waves = 16 rows × one quarter; quarter slice (2 MB) L2-resident,
// phased via dispatch order. Wave w: lane group g owns row w*4+g; lane
// m=l&15 owns 4 cols (u16x4 = 8B; 16 lanes = one full 128B line; 4 lines in
// flight per gather instruction). All 32 gathers prefetched to registers.
// ---------------------------------------------------------------------------
__global__ __launch_bounds__(256) void k_gather(const u16* __restrict__ nnf,
                                                const float* __restrict__ wts,
                                                const float* __restrict__ prm,
                                                const int* __restrict__ coords,
                                                float* __restrict__ out) {
  const int q  = blockIdx.x >> 10;    // 0..3
  const int rg = blockIdx.x & 1023;   // 16-row group
  const int tid = threadIdx.x;

  __shared__ int   s_idx[512];        // [16 rows][32 k]
  __shared__ float s_ew[512];

  {
    int base = rg * 512 + tid * 2;
    int2  c2 = *(const int2*)(coords + base);
    f32x2 w2 = __builtin_nontemporal_load((const f32x2*)(wts + base));
    f32x2 p2 = __builtin_nontemporal_load((const f32x2*)(prm + base));
    s_idx[tid * 2]     = c2.x;
    s_idx[tid * 2 + 1] = c2.y;
    s_ew[tid * 2]      = w2.x * p2.x;
    s_ew[tid * 2 + 1]  = w2.y * p2.y;
  }
  __syncthreads();

  const int w = tid >> 6;
  const int l = tid & 63;
  const int g = l >> 4;
  const int m = l & 15;
  const int rl = w * 4 + g;           // row-local 0..15
  const int row = rg * 16 + rl;       // 0..16383
  const int kbase = rl * 32;
  const u16* colp = nnf + q * 64 + m * 4;

  u16x4 v[32];
  #pragma unroll
  for (int k = 0; k < 32; ++k) {
    int idx = s_idx[kbase + k];       // uniform per 16-lane group
    v[k] = *(const u16x4*)(colp + ((size_t)idx << 8));
  }

  float acc[4] = {0.f, 0.f, 0.f, 0.f};
  #pragma unroll
  for (int k = 0; k < 32; ++k) {
    float wgt = s_ew[kbase + k];
    #pragma unroll
    for (int j = 0; j < 4; ++j)
      acc[j] += wgt * b2f(v[k][j]);
  }

  u16x4 sv = *(const u16x4*)(colp + ((size_t)row << 8));
  f32x4 o;
  o.x = fmaxf(b2f(sv.x) + acc[0], 0.f);
  o.y = fmaxf(b2f(sv.y) + acc[1], 0.f);
  o.z = fmaxf(b2f(sv.z) + acc[2], 0.f);
  o.w = fmaxf(b2f(sv.w) + acc[3], 0.f);
  __builtin_nontemporal_store(o, (f32x4*)(out + (size_t)row * 256 + q * 64 + m * 4));
}

// ---------------------------------------------------------------------------
extern "C" void kernel_launch(void* const* d_in, const int* in_sizes, int n_in,
                              void* d_out, int out_size, void* d_ws, size_t ws_size,
                              hipStream_t stream) {
  const float* node = (const float*)d_in[0];
  const float* cond = (const float*)d_in[1];
  const float* Wc   = (const float*)d_in[2];
  const float* bc   = (const float*)d_in[3];
  const float* Wf   = (const float*)d_in[4];
  const float* bf   = (const float*)d_in[5];
  const float* wts  = (const float*)d_in[6];
  const float* prm  = (const float*)d_in[7];
  const int* coords = (const int*)d_in[8];
  float* out = (float*)d_out;

  char* ws = (char*)d_ws;
  float* gbp = (float*)ws;                        // 2*8*512 f32 = 32 KB
  u16* Wp    = (u16*)(ws + 32768);                // 128 KB
  u16* nnf   = (u16*)(ws + 32768 + 131072);       // 8 MB  (total 8552448 B)

  k_prep<<<dim3(96), dim3(256), 0, stream>>>(Wf, Wp, cond, Wc, gbp);
  k_film<<<dim3(1024), dim3(256), 0, stream>>>(node, Wp, bf, gbp, bc, nnf);
  k_gather<<<dim3(4096), dim3(256), 0, stream>>>(nnf, wts, prm, coords, out);
}